// Round 4
// baseline (142.914 us; speedup 1.0000x reference)
//
#include <hip/hip_runtime.h>
#include <math.h>

// FBPINN PoU: S=64 subdomains, N=65536 points, W=64.
//   Phase 1: evaluate each subnet on a per-subdomain dense grid:
//            GK=5120 global grid, WIDTH=1024 samples per subdomain
//            (half-width 512/5120 = 0.1 >= PoU window 6/63 = 0.0952;
//            lerp error ~1e-7 << 7.3e-3 tol).
//            Wave-pair structure: 2 waves own one 64-point group; each wave
//            computes 32 of the 64 neurons with h[64]+acc[32] fully in
//            registers (constant indices, full unroll). LDS only for the
//            32-write/64-read per-layer exchange. Weights stream as
//            wave-uniform s_load_dwordx16 rows (imm offsets off one base).
//   Phase 2: per point, lerp the 12 nearest subnets + Gaussian PoU combine
//            (nearest dropped center >= 4.06 sigma -> rel weight ~1e-4).

#define GK     5120
#define WIDTH  1024
#define HALFW  512

__device__ __forceinline__ int glo_of(int s) {
    int g = (s * GK + 31) / 63 - HALFW;
    g = g < 0 ? 0 : g;
    const int hi = GK - (WIDTH - 1);
    g = g > hi ? hi : g;
    return g;
}

__device__ __forceinline__ float tanh_fast(float v) {
    // tanh(v) = 1 - 2/(exp(2v)+1); |v| <= ~7 here.
    float e = __expf(2.0f * v);
    return 1.0f - 2.0f * __builtin_amdgcn_rcpf(e + 1.0f);
}

// ---------------------------------------------------------------------------
// Phase 1. Grid: 512 blocks x 256 threads. Block = 2 point-groups; wave pair
// (neuron halves) per group. 2048 waves total = 2 waves/SIMD exactly.
// ---------------------------------------------------------------------------
__global__ __launch_bounds__(256, 2) void eval_grid(
    const float* __restrict__ W0, const float* __restrict__ b0,
    const float* __restrict__ W1, const float* __restrict__ b1,
    const float* __restrict__ W2, const float* __restrict__ b2,
    const float* __restrict__ W3, const float* __restrict__ b3,
    float* __restrict__ U)
{
    const int lane = (int)threadIdx.x & 63;
    const int wv   = __builtin_amdgcn_readfirstlane((int)(threadIdx.x >> 6));
    const int grp  = wv >> 1;            // point-group within block (0/1)
    const int vb   = (wv & 1) * 32;      // neuron half (0 or 32), uniform

    const int gid   = blockIdx.x * 2 + grp;       // 0..1023
    const int s     = gid >> 4;                   // subdomain
    const int chunk = gid & 15;                   // 16 chunks of 64 points
    const int p     = chunk * 64 + lane;          // 0..1023
    const int glo   = glo_of(s);
    const float x   = (float)(glo + p) * (1.0f / (float)GK);

    const float* __restrict__ w0  = W0 + s * 64;
    const float* __restrict__ bb0 = b0 + s * 64;
    const float* __restrict__ w1  = W1 + s * 4096;
    const float* __restrict__ bb1 = b1 + s * 64;
    const float* __restrict__ w2  = W2 + s * 4096;
    const float* __restrict__ bb2 = b2 + s * 64;
    const float* __restrict__ w3  = W3 + s * 64;

    __shared__ float H[2][64][64];                // 32 KiB

    // ---- layer 0: this wave's 32 neurons
#pragma unroll
    for (int j = 0; j < 32; ++j)
        H[grp][vb + j][lane] = tanh_fast(fmaf(w0[vb + j], x, bb0[vb + j]));
    __syncthreads();

    float h[64];
    float acc[32];

    // ---- layer 1
#pragma unroll
    for (int i = 0; i < 64; ++i) h[i] = H[grp][i][lane];
#pragma unroll
    for (int j = 0; j < 32; ++j) {
        const float* __restrict__ row = w1 + (vb + j) * 64;   // uniform base
        float a = bb1[vb + j];
#pragma unroll
        for (int i = 0; i < 64; ++i) a = fmaf(row[i], h[i], a);
        acc[j] = tanh_fast(a);
    }
    __syncthreads();                    // everyone done reading H0
#pragma unroll
    for (int j = 0; j < 32; ++j) H[grp][vb + j][lane] = acc[j];
    __syncthreads();

    // ---- layer 2
#pragma unroll
    for (int i = 0; i < 64; ++i) h[i] = H[grp][i][lane];
#pragma unroll
    for (int j = 0; j < 32; ++j) {
        const float* __restrict__ row = w2 + (vb + j) * 64;
        float a = bb2[vb + j];
#pragma unroll
        for (int i = 0; i < 64; ++i) a = fmaf(row[i], h[i], a);
        acc[j] = tanh_fast(a);
    }
    __syncthreads();                    // everyone done reading H1
#pragma unroll
    for (int j = 0; j < 32; ++j) H[grp][vb + j][lane] = acc[j];
    __syncthreads();

    // ---- layer 3: both halves compute u (64 FMA, trivial); half 0 stores
#pragma unroll
    for (int i = 0; i < 64; ++i) h[i] = H[grp][i][lane];
    float u = b3[s];
#pragma unroll
    for (int i = 0; i < 64; ++i) u = fmaf(w3[i], h[i], u);
    if ((wv & 1) == 0)
        U[s * WIDTH + p] = u;
}

// ---------------------------------------------------------------------------
// Phase 2: PoU combine over the 12 nearest subdomains via table lerp.
// 512 blocks x 128 threads -> 2 blocks/CU for gather-latency TLP.
// ---------------------------------------------------------------------------
__global__ __launch_bounds__(128) void combine(
    const float* __restrict__ x_in, const float* __restrict__ U,
    float* __restrict__ out, int N)
{
    int n = blockIdx.x * 128 + (int)threadIdx.x;
    if (n >= N) return;
    float x = x_in[n];

    int jf = (int)floorf(x * 63.0f);    // floor center index
    int lo = jf - 5;                    // window jf-5 .. jf+6 (12 subnets)
    lo = lo < 0 ? 0 : (lo > 52 ? 52 : lo);

    const float inv_sigma = 64.0f / 1.5f;
    const float t_all = x * (float)GK;

    float u0v[12], u1v[12], fracv[12], wv[12];
#pragma unroll
    for (int k = 0; k < 12; ++k) {
        int s = lo + k;
        int glo = glo_of(s);
        float t = t_all - (float)glo;
        int it = (int)floorf(t);
        it = it < 0 ? 0 : (it > WIDTH - 2 ? WIDTH - 2 : it);
        fracv[k] = t - (float)it;
        const float* __restrict__ row = U + s * WIDTH + it;
        u0v[k] = row[0];
        u1v[k] = row[1];
        float d = (x - (float)s * (1.0f / 63.0f)) * inv_sigma;
        wv[k] = __expf(-0.5f * d * d);
    }

    float num = 0.0f, den = 0.0f;
#pragma unroll
    for (int k = 0; k < 12; ++k) {
        float u = fmaf(fracv[k], u1v[k] - u0v[k], u0v[k]);
        num = fmaf(wv[k], u, num);
        den += wv[k];
    }

    out[n] = tanh_fast(5.0f * x) * num * __builtin_amdgcn_rcpf(den);
}

// ---------------------------------------------------------------------------
extern "C" void kernel_launch(void* const* d_in, const int* in_sizes, int n_in,
                              void* d_out, int out_size, void* d_ws, size_t ws_size,
                              hipStream_t stream) {
    const float* x  = (const float*)d_in[0];
    const float* W0 = (const float*)d_in[1];
    const float* b0 = (const float*)d_in[2];
    const float* W1 = (const float*)d_in[3];
    const float* b1 = (const float*)d_in[4];
    const float* W2 = (const float*)d_in[5];
    const float* b2 = (const float*)d_in[6];
    const float* W3 = (const float*)d_in[7];
    const float* b3 = (const float*)d_in[8];

    float* U   = (float*)d_ws;     // 64 * 1024 * 4 B = 256 KiB scratch
    float* out = (float*)d_out;

    eval_grid<<<dim3(512), dim3(256), 0, stream>>>(
        W0, b0, W1, b1, W2, b2, W3, b3, U);
    combine<<<dim3(512), dim3(128), 0, stream>>>(x, U, out, 65536);
}

// Round 5
// 100.430 us; speedup vs baseline: 1.4230x; 1.4230x over previous
//
#include <hip/hip_runtime.h>
#include <math.h>

// FBPINN PoU: S=64 subdomains, N=65536 points, W=64.
//   Phase 1: evaluate each subnet on a dense grid: GK=5120, WIDTH=1024
//            samples/subdomain (half-width 0.1 >= PoU window 6/63=0.0952;
//            lerp error ~1e-7). Block = 64 points x 4 waves (16 neurons
//            each). Fixes vs rounds 2-4 (all defeated by LDS-remat /
//            scalar-path stalls, VALUBusy <= 52%):
//              * h[64] pinned in VGPRs via empty asm (remat impossible)
//              * W1/W2 staged in LDS, consumed as wave-uniform ds_read_b128
//                -> all-VGPR FMAs, no SGPR prefetch wall
//              * layer-3 = cross-wave reduction of register partials
//   Phase 2: lerp the 12 nearest subnets + Gaussian PoU combine
//            (nearest dropped center >= 4.06 sigma).

#define GK     5120
#define WIDTH  1024
#define HALFW  512

__device__ __forceinline__ int glo_of(int s) {
    int g = (s * GK + 31) / 63 - HALFW;
    g = g < 0 ? 0 : g;
    const int hi = GK - (WIDTH - 1);
    g = g > hi ? hi : g;
    return g;
}

__device__ __forceinline__ float tanh_fast(float v) {
    // tanh(v) = 1 - 2/(exp(2v)+1); |v| <= ~7 here.
    float e = __expf(2.0f * v);
    return 1.0f - 2.0f * __builtin_amdgcn_rcpf(e + 1.0f);
}

// ---------------------------------------------------------------------------
// Phase 1. Grid: 64 subdomains x 16 chunks = 1024 blocks x 256 threads
// (4 waves/SIMD demand; LDS 33 KB -> 4 blocks/CU resident).
// ---------------------------------------------------------------------------
__global__ __launch_bounds__(256, 4) void eval_grid(
    const float* __restrict__ W0, const float* __restrict__ b0,
    const float* __restrict__ W1, const float* __restrict__ b1,
    const float* __restrict__ W2, const float* __restrict__ b2,
    const float* __restrict__ W3, const float* __restrict__ b3,
    float* __restrict__ U)
{
    const int tid  = (int)threadIdx.x;
    const int lane = tid & 63;
    const int wv   = __builtin_amdgcn_readfirstlane(tid >> 6);
    const int vb   = wv * 16;                      // this wave's neuron base

    const int s     = blockIdx.x >> 4;
    const int chunk = blockIdx.x & 15;
    const int p     = chunk * 64 + lane;           // 0..1023
    const int glo   = glo_of(s);
    const float x   = (float)(glo + p) * (1.0f / (float)GK);

    __shared__ float H[64][64];    // 16 KiB, [neuron][lane] -> 2-way, free
    __shared__ float Wb[4096];     // 16 KiB, current layer's weights
    __shared__ float P[4][64];     // layer-3 partials

    float4* __restrict__ wlds = (float4*)Wb;

    // ---- stage W1 into registers (coalesced float4; 16 floats/thread)
    const float4* __restrict__ g1 = (const float4*)(W1 + s * 4096);
    float4 wst[4];
#pragma unroll
    for (int q = 0; q < 4; ++q) wst[q] = g1[q * 256 + tid];

    // ---- layer 0 (tiny: scalar weights)
    const float* __restrict__ w0  = W0 + s * 64;
    const float* __restrict__ bb0 = b0 + s * 64;
#pragma unroll
    for (int j = 0; j < 16; ++j)
        H[vb + j][lane] = tanh_fast(fmaf(w0[vb + j], x, bb0[vb + j]));

    // ---- commit W1 to LDS
#pragma unroll
    for (int q = 0; q < 4; ++q) wlds[q * 256 + tid] = wst[q];
    __syncthreads();                               // H0 + W1 visible

    float h[64];
    float acc[16];

    // ================= layer 1 =================
#pragma unroll
    for (int i = 0; i < 64; ++i) h[i] = H[i][lane];
#pragma unroll
    for (int i = 0; i < 64; ++i) asm volatile("" : "+v"(h[i]));  // pin in VGPR

    const float* __restrict__ bb1 = b1 + s * 64;
#pragma unroll
    for (int j = 0; j < 16; ++j) acc[j] = bb1[vb + j];
#pragma unroll
    for (int wb = 0; wb < 4; ++wb) {
#pragma unroll
        for (int j = 0; j < 16; ++j) {
            const float4* __restrict__ wr =
                (const float4*)&Wb[(vb + j) * 64 + wb * 16];
#pragma unroll
            for (int q = 0; q < 4; ++q) {
                float4 w = wr[q];
                int ib = wb * 16 + q * 4;
                acc[j] = fmaf(w.x, h[ib + 0], acc[j]);
                acc[j] = fmaf(w.y, h[ib + 1], acc[j]);
                acc[j] = fmaf(w.z, h[ib + 2], acc[j]);
                acc[j] = fmaf(w.w, h[ib + 3], acc[j]);
            }
        }
    }

    // issue W2 global loads now; vmcnt drain lands after the barrier
    const float4* __restrict__ g2 = (const float4*)(W2 + s * 4096);
#pragma unroll
    for (int q = 0; q < 4; ++q) wst[q] = g2[q * 256 + tid];

    __syncthreads();                               // all waves done with W1/H0
#pragma unroll
    for (int j = 0; j < 16; ++j) H[vb + j][lane] = tanh_fast(acc[j]);
#pragma unroll
    for (int q = 0; q < 4; ++q) wlds[q * 256 + tid] = wst[q];
    __syncthreads();                               // H1 + W2 visible

    // ================= layer 2 =================
#pragma unroll
    for (int i = 0; i < 64; ++i) h[i] = H[i][lane];
#pragma unroll
    for (int i = 0; i < 64; ++i) asm volatile("" : "+v"(h[i]));

    const float* __restrict__ bb2 = b2 + s * 64;
#pragma unroll
    for (int j = 0; j < 16; ++j) acc[j] = bb2[vb + j];
#pragma unroll
    for (int wb = 0; wb < 4; ++wb) {
#pragma unroll
        for (int j = 0; j < 16; ++j) {
            const float4* __restrict__ wr =
                (const float4*)&Wb[(vb + j) * 64 + wb * 16];
#pragma unroll
            for (int q = 0; q < 4; ++q) {
                float4 w = wr[q];
                int ib = wb * 16 + q * 4;
                acc[j] = fmaf(w.x, h[ib + 0], acc[j]);
                acc[j] = fmaf(w.y, h[ib + 1], acc[j]);
                acc[j] = fmaf(w.z, h[ib + 2], acc[j]);
                acc[j] = fmaf(w.w, h[ib + 3], acc[j]);
            }
        }
    }

    // ================= layer 3 =================
    // This wave's acc[16] ARE h2 for neurons vb..vb+15 -> register partials,
    // no H2 exchange needed.
    const float* __restrict__ w3 = W3 + s * 64;
    float pu = 0.0f;
#pragma unroll
    for (int j = 0; j < 16; ++j)
        pu = fmaf(w3[vb + j], tanh_fast(acc[j]), pu);
    P[wv][lane] = pu;
    __syncthreads();
    if (wv == 0) {
        float u = b3[s] + P[0][lane] + P[1][lane] + P[2][lane] + P[3][lane];
        U[s * WIDTH + p] = u;
    }
}

// ---------------------------------------------------------------------------
// Phase 2: PoU combine over the 12 nearest subdomains via table lerp.
// ---------------------------------------------------------------------------
__global__ __launch_bounds__(256) void combine(
    const float* __restrict__ x_in, const float* __restrict__ U,
    float* __restrict__ out, int N)
{
    int n = blockIdx.x * 256 + (int)threadIdx.x;
    if (n >= N) return;
    float x = x_in[n];

    int jf = (int)floorf(x * 63.0f);    // floor center index
    int lo = jf - 5;                    // window jf-5 .. jf+6 (12 subnets)
    lo = lo < 0 ? 0 : (lo > 52 ? 52 : lo);

    const float inv_sigma = 64.0f / 1.5f;
    const float t_all = x * (float)GK;

    float u0v[12], u1v[12], fracv[12], wvv[12];
#pragma unroll
    for (int k = 0; k < 12; ++k) {
        int s = lo + k;
        int glo = glo_of(s);
        float t = t_all - (float)glo;
        int it = (int)floorf(t);
        it = it < 0 ? 0 : (it > WIDTH - 2 ? WIDTH - 2 : it);
        fracv[k] = t - (float)it;
        const float* __restrict__ row = U + s * WIDTH + it;
        u0v[k] = row[0];
        u1v[k] = row[1];
        float d = (x - (float)s * (1.0f / 63.0f)) * inv_sigma;
        wvv[k] = __expf(-0.5f * d * d);
    }

    float num = 0.0f, den = 0.0f;
#pragma unroll
    for (int k = 0; k < 12; ++k) {
        float u = fmaf(fracv[k], u1v[k] - u0v[k], u0v[k]);
        num = fmaf(wvv[k], u, num);
        den += wvv[k];
    }

    out[n] = tanh_fast(5.0f * x) * num * __builtin_amdgcn_rcpf(den);
}

// ---------------------------------------------------------------------------
extern "C" void kernel_launch(void* const* d_in, const int* in_sizes, int n_in,
                              void* d_out, int out_size, void* d_ws, size_t ws_size,
                              hipStream_t stream) {
    const float* x  = (const float*)d_in[0];
    const float* W0 = (const float*)d_in[1];
    const float* b0 = (const float*)d_in[2];
    const float* W1 = (const float*)d_in[3];
    const float* b1 = (const float*)d_in[4];
    const float* W2 = (const float*)d_in[5];
    const float* b2 = (const float*)d_in[6];
    const float* W3 = (const float*)d_in[7];
    const float* b3 = (const float*)d_in[8];

    float* U   = (float*)d_ws;     // 64 * 1024 * 4 B = 256 KiB scratch
    float* out = (float*)d_out;

    eval_grid<<<dim3(1024), dim3(256), 0, stream>>>(
        W0, b0, W1, b1, W2, b2, W3, b3, U);
    combine<<<dim3(256), dim3(256), 0, stream>>>(x, U, out, 65536);
}

// Round 6
// 99.476 us; speedup vs baseline: 1.4367x; 1.0096x over previous
//
#include <hip/hip_runtime.h>
#include <math.h>

// FBPINN PoU: S=64 subdomains, N=65536 points, W=64.
//   Phase 1: evaluate each subnet on a dense grid: GK=5120, WIDTH=1024
//            samples/subdomain (half-width 0.1 >= PoU window 6/63=0.0952;
//            lerp error ~1e-7). Block = 64 points x 4 waves (16 neurons
//            each). Round-6 synthesis of what the counters proved:
//              * r3: hc[16]+acc[16] chunked register blocking -> no spills
//              * r5: weights via LDS (wave-uniform ds_read_b128 broadcast)
//                -> no SGPR/s_load prefetch wall
//              * asm pins ONLY on the small arrays (~70 VGPR < 128 cap;
//                r5's h[64] pin overflowed the cap -> 33 MB scratch spill)
//   Phase 2: lerp the 12 nearest subnets + Gaussian PoU combine.

#define GK     5120
#define WIDTH  1024
#define HALFW  512

__device__ __forceinline__ int glo_of(int s) {
    int g = (s * GK + 31) / 63 - HALFW;
    g = g < 0 ? 0 : g;
    const int hi = GK - (WIDTH - 1);
    g = g > hi ? hi : g;
    return g;
}

__device__ __forceinline__ float tanh_fast(float v) {
    // tanh(v) = 1 - 2/(exp(2v)+1); |v| <= ~7 here.
    float e = __expf(2.0f * v);
    return 1.0f - 2.0f * __builtin_amdgcn_rcpf(e + 1.0f);
}

// ---------------------------------------------------------------------------
// Phase 1. Grid: 64 subdomains x 16 chunks = 1024 blocks x 256 threads.
// LDS 33 KB -> 4 blocks/CU resident; demand 16 waves/CU = 4/SIMD.
// ---------------------------------------------------------------------------
__global__ __launch_bounds__(256, 4) void eval_grid(
    const float* __restrict__ W0, const float* __restrict__ b0,
    const float* __restrict__ W1, const float* __restrict__ b1,
    const float* __restrict__ W2, const float* __restrict__ b2,
    const float* __restrict__ W3, const float* __restrict__ b3,
    float* __restrict__ U)
{
    const int tid  = (int)threadIdx.x;
    const int lane = tid & 63;
    const int wv   = __builtin_amdgcn_readfirstlane(tid >> 6);
    const int vb   = wv * 16;                      // this wave's neuron base

    const int s     = blockIdx.x >> 4;
    const int chunk = blockIdx.x & 15;
    const int p     = chunk * 64 + lane;           // 0..1023
    const int glo   = glo_of(s);
    const float x   = (float)(glo + p) * (1.0f / (float)GK);

    __shared__ float H[64][64];    // 16 KiB, [neuron][lane]: conflict-free
    __shared__ float Wb[4096];     // 16 KiB, current layer's weights
    __shared__ float P[4][64];     // layer-3 partials

    float4* __restrict__ wlds = (float4*)Wb;

    // ---- stage W1 into registers (coalesced float4; 16 floats/thread)
    const float4* __restrict__ g1 = (const float4*)(W1 + s * 4096);
    float4 wst[4];
#pragma unroll
    for (int q = 0; q < 4; ++q) wst[q] = g1[q * 256 + tid];

    // ---- layer 0 (tiny: scalar weights)
    const float* __restrict__ w0  = W0 + s * 64;
    const float* __restrict__ bb0 = b0 + s * 64;
#pragma unroll
    for (int j = 0; j < 16; ++j)
        H[vb + j][lane] = tanh_fast(fmaf(w0[vb + j], x, bb0[vb + j]));

    // ---- commit W1 to LDS
#pragma unroll
    for (int q = 0; q < 4; ++q) wlds[q * 256 + tid] = wst[q];
    __syncthreads();                               // H0 + W1 visible

    float acc[16];
    const float* __restrict__ bb1 = b1 + s * 64;

    // ================= layer 1 =================
#pragma unroll
    for (int j = 0; j < 16; ++j) acc[j] = bb1[vb + j];
#pragma unroll
    for (int j = 0; j < 16; ++j) asm volatile("" : "+v"(acc[j]));
#pragma unroll
    for (int wb = 0; wb < 4; ++wb) {
        float hc[16];
#pragma unroll
        for (int i = 0; i < 16; ++i) hc[i] = H[wb * 16 + i][lane];
#pragma unroll
        for (int i = 0; i < 16; ++i) asm volatile("" : "+v"(hc[i]));
#pragma unroll
        for (int j = 0; j < 16; ++j) {
            const float4* __restrict__ wr =
                (const float4*)&Wb[(vb + j) * 64 + wb * 16];
#pragma unroll
            for (int q = 0; q < 4; ++q) {
                float4 w = wr[q];
                acc[j] = fmaf(w.x, hc[q * 4 + 0], acc[j]);
                acc[j] = fmaf(w.y, hc[q * 4 + 1], acc[j]);
                acc[j] = fmaf(w.z, hc[q * 4 + 2], acc[j]);
                acc[j] = fmaf(w.w, hc[q * 4 + 3], acc[j]);
            }
        }
    }

    // issue W2 global loads now; they drain across the barrier
    const float4* __restrict__ g2 = (const float4*)(W2 + s * 4096);
#pragma unroll
    for (int q = 0; q < 4; ++q) wst[q] = g2[q * 256 + tid];

    __syncthreads();                               // all waves done with W1/H0
#pragma unroll
    for (int j = 0; j < 16; ++j) H[vb + j][lane] = tanh_fast(acc[j]);
#pragma unroll
    for (int q = 0; q < 4; ++q) wlds[q * 256 + tid] = wst[q];
    __syncthreads();                               // H1 + W2 visible

    // ================= layer 2 =================
    const float* __restrict__ bb2 = b2 + s * 64;
#pragma unroll
    for (int j = 0; j < 16; ++j) acc[j] = bb2[vb + j];
#pragma unroll
    for (int j = 0; j < 16; ++j) asm volatile("" : "+v"(acc[j]));
#pragma unroll
    for (int wb = 0; wb < 4; ++wb) {
        float hc[16];
#pragma unroll
        for (int i = 0; i < 16; ++i) hc[i] = H[wb * 16 + i][lane];
#pragma unroll
        for (int i = 0; i < 16; ++i) asm volatile("" : "+v"(hc[i]));
#pragma unroll
        for (int j = 0; j < 16; ++j) {
            const float4* __restrict__ wr =
                (const float4*)&Wb[(vb + j) * 64 + wb * 16];
#pragma unroll
            for (int q = 0; q < 4; ++q) {
                float4 w = wr[q];
                acc[j] = fmaf(w.x, hc[q * 4 + 0], acc[j]);
                acc[j] = fmaf(w.y, hc[q * 4 + 1], acc[j]);
                acc[j] = fmaf(w.z, hc[q * 4 + 2], acc[j]);
                acc[j] = fmaf(w.w, hc[q * 4 + 3], acc[j]);
            }
        }
    }

    // ================= layer 3 =================
    // This wave's acc[16] ARE h2 for neurons vb..vb+15 -> register partials.
    const float* __restrict__ w3 = W3 + s * 64;
    float pu = 0.0f;
#pragma unroll
    for (int j = 0; j < 16; ++j)
        pu = fmaf(w3[vb + j], tanh_fast(acc[j]), pu);
    P[wv][lane] = pu;
    __syncthreads();
    if (wv == 0) {
        float u = b3[s] + P[0][lane] + P[1][lane] + P[2][lane] + P[3][lane];
        U[s * WIDTH + p] = u;
    }
}

// ---------------------------------------------------------------------------
// Phase 2: PoU combine over the 12 nearest subdomains via table lerp.
// ---------------------------------------------------------------------------
__global__ __launch_bounds__(256) void combine(
    const float* __restrict__ x_in, const float* __restrict__ U,
    float* __restrict__ out, int N)
{
    int n = blockIdx.x * 256 + (int)threadIdx.x;
    if (n >= N) return;
    float x = x_in[n];

    int jf = (int)floorf(x * 63.0f);    // floor center index
    int lo = jf - 5;                    // window jf-5 .. jf+6 (12 subnets)
    lo = lo < 0 ? 0 : (lo > 52 ? 52 : lo);

    const float inv_sigma = 64.0f / 1.5f;
    const float t_all = x * (float)GK;

    float u0v[12], u1v[12], fracv[12], wvv[12];
#pragma unroll
    for (int k = 0; k < 12; ++k) {
        int s = lo + k;
        int glo = glo_of(s);
        float t = t_all - (float)glo;
        int it = (int)floorf(t);
        it = it < 0 ? 0 : (it > WIDTH - 2 ? WIDTH - 2 : it);
        fracv[k] = t - (float)it;
        const float* __restrict__ row = U + s * WIDTH + it;
        u0v[k] = row[0];
        u1v[k] = row[1];
        float d = (x - (float)s * (1.0f / 63.0f)) * inv_sigma;
        wvv[k] = __expf(-0.5f * d * d);
    }

    float num = 0.0f, den = 0.0f;
#pragma unroll
    for (int k = 0; k < 12; ++k) {
        float u = fmaf(fracv[k], u1v[k] - u0v[k], u0v[k]);
        num = fmaf(wvv[k], u, num);
        den += wvv[k];
    }

    out[n] = tanh_fast(5.0f * x) * num * __builtin_amdgcn_rcpf(den);
}

// ---------------------------------------------------------------------------
extern "C" void kernel_launch(void* const* d_in, const int* in_sizes, int n_in,
                              void* d_out, int out_size, void* d_ws, size_t ws_size,
                              hipStream_t stream) {
    const float* x  = (const float*)d_in[0];
    const float* W0 = (const float*)d_in[1];
    const float* b0 = (const float*)d_in[2];
    const float* W1 = (const float*)d_in[3];
    const float* b1 = (const float*)d_in[4];
    const float* W2 = (const float*)d_in[5];
    const float* b2 = (const float*)d_in[6];
    const float* W3 = (const float*)d_in[7];
    const float* b3 = (const float*)d_in[8];

    float* U   = (float*)d_ws;     // 64 * 1024 * 4 B = 256 KiB scratch
    float* out = (float*)d_out;

    eval_grid<<<dim3(1024), dim3(256), 0, stream>>>(
        W0, b0, W1, b1, W2, b2, W3, b3, U);
    combine<<<dim3(256), dim3(256), 0, stream>>>(x, U, out, 65536);
}

// Round 8
// 81.939 us; speedup vs baseline: 1.7441x; 1.2140x over previous
//
#include <hip/hip_runtime.h>
#include <math.h>

// FBPINN PoU: S=64 subdomains, N=65536 points, W=64.
// Round 8 = round 7 with the cvt_pkrtz type fixed (__fp16 vs _Float16).
// Layers 1/2 via v_mfma_f32_16x16x32_f16.
//   Rationale (r6 post-mortem): the per-CU LDS pipe is shared by 4 SIMDs;
//   fp32 FMA needs 1 b128 weight read per 4 FMA insts -> 6.75x LDS
//   oversubscription (model matched 41.5 us observed). MFMA internalizes
//   operand broadcast: 10 LDS ops + 8 MFMA per wave-layer.
//   f16 (not bf16): 10 mantissa bits, fp32 accumulation -> added err ~5e-4.
// Phase 1: per-subnet dense grid GK=5120, WIDTH=1024 (lerp err ~1e-7).
//   Block = (subdomain, 64-point chunk), 4 waves. Wave wv owns C m-tile
//   mi=wv (v = 16wv..16wv+15) x all 4 n-tiles (p).
//   Layouts (verified per docs): C/D col=lane&15, row=(lane>>4)*4+reg;
//   A[m=lane&15][k=(lane>>4)*8+j]; B-frag = B^T rows (Ht[p][w]).
// Phase 2: lerp 12 nearest subnets + Gaussian PoU combine.

#define GK     5120
#define WIDTH  1024
#define HALFW  512
#define SW     36      // u32 words per LDS row: 32 data + 4 pad = 144 B (16B-aligned)

typedef _Float16 half8  __attribute__((ext_vector_type(8)));
typedef __fp16   fp16x2 __attribute__((ext_vector_type(2)));
typedef float    f32x4  __attribute__((ext_vector_type(4)));

__device__ __forceinline__ int glo_of(int s) {
    int g = (s * GK + 31) / 63 - HALFW;
    g = g < 0 ? 0 : g;
    const int hi = GK - (WIDTH - 1);
    g = g > hi ? hi : g;
    return g;
}

__device__ __forceinline__ float tanh_fast(float v) {
    // tanh(v) = 1 - 2/(exp(2v)+1); |v| <= ~7 here.
    float e = __expf(2.0f * v);
    return 1.0f - 2.0f * __builtin_amdgcn_rcpf(e + 1.0f);
}

__device__ __forceinline__ unsigned pkh(float a, float b) {
    fp16x2 h = __builtin_amdgcn_cvt_pkrtz(a, b);   // a->lo, b->hi
    return __builtin_bit_cast(unsigned, h);
}

// ---------------------------------------------------------------------------
// Phase 1. Grid: 64 subdomains x 16 chunks = 1024 blocks x 256 threads.
// ---------------------------------------------------------------------------
__global__ __launch_bounds__(256, 4) void eval_grid(
    const float* __restrict__ W0, const float* __restrict__ b0,
    const float* __restrict__ W1, const float* __restrict__ b1,
    const float* __restrict__ W2, const float* __restrict__ b2,
    const float* __restrict__ W3, const float* __restrict__ b3,
    float* __restrict__ U)
{
    const int tid  = (int)threadIdx.x;
    const int lane = tid & 63;
    const int wv   = __builtin_amdgcn_readfirstlane(tid >> 6);
    const int quad = lane >> 4;
    const int a16  = lane & 15;

    const int s     = blockIdx.x >> 4;
    const int chunk = blockIdx.x & 15;
    const int glo   = glo_of(s);
    const float x   = (float)(glo + chunk * 64 + lane) * (1.0f / (float)GK);

    __shared__ unsigned HtA[64 * SW];   // h0, f16-pairs, rows = p
    __shared__ unsigned HtB[64 * SW];   // h1
    __shared__ unsigned Wa1[64 * SW];   // W1 f16, rows = v (A layout)
    __shared__ unsigned Wa2[64 * SW];
    __shared__ float    Pw[4][4][16];   // layer-3 partials [wv][ni][a16]

    // ---- stage W1, W2 as f16 rows (one-time; coalesced float4 loads)
    const float4* __restrict__ g1 = (const float4*)(W1 + s * 4096);
    const float4* __restrict__ g2 = (const float4*)(W2 + s * 4096);
#pragma unroll
    for (int q = 0; q < 4; ++q) {
        int li = q * 256 + tid;              // float4 index 0..1023
        int v  = li >> 4;                    // row
        int wd = 2 * (li & 15);              // word col (2 words per float4)
        float4 f1 = g1[li];
        float4 f2 = g2[li];
        Wa1[v * SW + wd]     = pkh(f1.x, f1.y);
        Wa1[v * SW + wd + 1] = pkh(f1.z, f1.w);
        Wa2[v * SW + wd]     = pkh(f2.x, f2.y);
        Wa2[v * SW + wd + 1] = pkh(f2.z, f2.w);
    }

    // ---- layer 0: wave wv computes v = 16wv..16wv+15 for its lane's point
    const float* __restrict__ w0  = W0 + s * 64;
    const float* __restrict__ bb0 = b0 + s * 64;
#pragma unroll
    for (int j = 0; j < 16; j += 2) {
        int v = 16 * wv + j;
        float h0 = tanh_fast(fmaf(w0[v],     x, bb0[v]));
        float h1 = tanh_fast(fmaf(w0[v + 1], x, bb0[v + 1]));
        HtA[lane * SW + (v >> 1)] = pkh(h0, h1);
    }
    __syncthreads();                         // h0 + Wa1 + Wa2 visible

    const int vbase = 16 * wv + 4 * quad;    // this lane's C rows (v)
    f32x4 acc[4];

    // ================= layer 1 (MFMA) =================
    {
        const float* __restrict__ b1g = b1 + s * 64;
        float bv[4];
#pragma unroll
        for (int r = 0; r < 4; ++r) bv[r] = b1g[vbase + r];
#pragma unroll
        for (int ni = 0; ni < 4; ++ni)
#pragma unroll
            for (int r = 0; r < 4; ++r) acc[ni][r] = bv[r];

        half8 afr[2];
#pragma unroll
        for (int ks = 0; ks < 2; ++ks)
            afr[ks] = *(const half8*)&Wa1[(16 * wv + a16) * SW + 16 * ks + 4 * quad];
#pragma unroll
        for (int ni = 0; ni < 4; ++ni) {
#pragma unroll
            for (int ks = 0; ks < 2; ++ks) {
                half8 bfr = *(const half8*)&HtA[(16 * ni + a16) * SW + 16 * ks + 4 * quad];
                acc[ni] = __builtin_amdgcn_mfma_f32_16x16x32_f16(afr[ks], bfr, acc[ni], 0, 0, 0);
            }
        }
        // tanh + pack h1 into HtB (rows = p, cols = v/2) — no WAR on HtA
#pragma unroll
        for (int ni = 0; ni < 4; ++ni) {
            int row  = (16 * ni + a16) * SW;
            int colb = 8 * wv + 2 * quad;
            HtB[row + colb]     = pkh(tanh_fast(acc[ni][0]), tanh_fast(acc[ni][1]));
            HtB[row + colb + 1] = pkh(tanh_fast(acc[ni][2]), tanh_fast(acc[ni][3]));
        }
    }
    __syncthreads();                         // h1 visible

    // ================= layer 2 (MFMA) =================
    {
        const float* __restrict__ b2g = b2 + s * 64;
        float bv[4];
#pragma unroll
        for (int r = 0; r < 4; ++r) bv[r] = b2g[vbase + r];
#pragma unroll
        for (int ni = 0; ni < 4; ++ni)
#pragma unroll
            for (int r = 0; r < 4; ++r) acc[ni][r] = bv[r];

        half8 afr[2];
#pragma unroll
        for (int ks = 0; ks < 2; ++ks)
            afr[ks] = *(const half8*)&Wa2[(16 * wv + a16) * SW + 16 * ks + 4 * quad];
#pragma unroll
        for (int ni = 0; ni < 4; ++ni) {
#pragma unroll
            for (int ks = 0; ks < 2; ++ks) {
                half8 bfr = *(const half8*)&HtB[(16 * ni + a16) * SW + 16 * ks + 4 * quad];
                acc[ni] = __builtin_amdgcn_mfma_f32_16x16x32_f16(afr[ks], bfr, acc[ni], 0, 0, 0);
            }
        }
    }

    // ================= layer 3: u[p] = b3 + sum_v w3[v]*tanh(h2[v][p]) ====
    {
        const float* __restrict__ w3g = W3 + s * 64;
        float w3r[4];
#pragma unroll
        for (int r = 0; r < 4; ++r) w3r[r] = w3g[vbase + r];
#pragma unroll
        for (int ni = 0; ni < 4; ++ni) {
            float pu = 0.0f;
#pragma unroll
            for (int r = 0; r < 4; ++r)
                pu = fmaf(w3r[r], tanh_fast(acc[ni][r]), pu);
            // sum over the 4 quads (v-subsets) for fixed p = 16ni + a16
            pu += __shfl_xor(pu, 16);
            pu += __shfl_xor(pu, 32);
            if (quad == 0) Pw[wv][ni][a16] = pu;
        }
    }
    __syncthreads();

    if (tid < 64) {
        float u = b3[s];
#pragma unroll
        for (int w = 0; w < 4; ++w) u += Pw[w][tid >> 4][tid & 15];
        U[s * WIDTH + chunk * 64 + tid] = u;
    }
}

// ---------------------------------------------------------------------------
// Phase 2: PoU combine over the 12 nearest subdomains via table lerp.
// ---------------------------------------------------------------------------
__global__ __launch_bounds__(256) void combine(
    const float* __restrict__ x_in, const float* __restrict__ U,
    float* __restrict__ out, int N)
{
    int n = blockIdx.x * 256 + (int)threadIdx.x;
    if (n >= N) return;
    float x = x_in[n];

    int jf = (int)floorf(x * 63.0f);    // floor center index
    int lo = jf - 5;                    // window jf-5 .. jf+6 (12 subnets)
    lo = lo < 0 ? 0 : (lo > 52 ? 52 : lo);

    const float inv_sigma = 64.0f / 1.5f;
    const float t_all = x * (float)GK;

    float u0v[12], u1v[12], fracv[12], wvv[12];
#pragma unroll
    for (int k = 0; k < 12; ++k) {
        int s = lo + k;
        int glo = glo_of(s);
        float t = t_all - (float)glo;
        int it = (int)floorf(t);
        it = it < 0 ? 0 : (it > WIDTH - 2 ? WIDTH - 2 : it);
        fracv[k] = t - (float)it;
        const float* __restrict__ row = U + s * WIDTH + it;
        u0v[k] = row[0];
        u1v[k] = row[1];
        float d = (x - (float)s * (1.0f / 63.0f)) * inv_sigma;
        wvv[k] = __expf(-0.5f * d * d);
    }

    float num = 0.0f, den = 0.0f;
#pragma unroll
    for (int k = 0; k < 12; ++k) {
        float u = fmaf(fracv[k], u1v[k] - u0v[k], u0v[k]);
        num = fmaf(wvv[k], u, num);
        den += wvv[k];
    }

    out[n] = tanh_fast(5.0f * x) * num * __builtin_amdgcn_rcpf(den);
}

// ---------------------------------------------------------------------------
extern "C" void kernel_launch(void* const* d_in, const int* in_sizes, int n_in,
                              void* d_out, int out_size, void* d_ws, size_t ws_size,
                              hipStream_t stream) {
    const float* x  = (const float*)d_in[0];
    const float* W0 = (const float*)d_in[1];
    const float* b0 = (const float*)d_in[2];
    const float* W1 = (const float*)d_in[3];
    const float* b1 = (const float*)d_in[4];
    const float* W2 = (const float*)d_in[5];
    const float* b2 = (const float*)d_in[6];
    const float* W3 = (const float*)d_in[7];
    const float* b3 = (const float*)d_in[8];

    float* U   = (float*)d_ws;     // 64 * 1024 * 4 B = 256 KiB scratch
    float* out = (float*)d_out;

    eval_grid<<<dim3(1024), dim3(256), 0, stream>>>(
        W0, b0, W1, b1, W2, b2, W3, b3, U);
    combine<<<dim3(256), dim3(256), 0, stream>>>(x, U, out, 65536);
}

// Round 9
// 80.617 us; speedup vs baseline: 1.7728x; 1.0164x over previous
//
#include <hip/hip_runtime.h>
#include <math.h>

// FBPINN PoU: S=64 subdomains, N=65536 points, W=64.
// Round 9 = round 8 (MFMA f16 layers 1/2, verified correct, absmax 1.95e-3)
// + XCD-aware block swizzle: s = blockIdx&63, chunk = blockIdx>>6.
//   Under round-robin XCD dispatch all 16 chunk-blocks of subdomain s land
//   on XCD s%8 -> weights fetched from HBM once per subdomain (not once per
//   XCD): FETCH 17 MB -> ~3 MB, and 15/16 of the staging loads become
//   ~200-cyc L2 hits instead of ~900-cyc HBM misses (r8's critical path).
// Phase 1: per-subnet dense grid GK=5120, WIDTH=1024 (lerp err ~1e-7).
//   Block = (subdomain, 64-point chunk), 4 waves. Wave wv owns C m-tile
//   mi=wv (v = 16wv..16wv+15) x all 4 n-tiles (p).
//   Layouts: C/D col=lane&15, row=(lane>>4)*4+reg; A[m=lane&15][k=quad*8+j];
//   B-frag = B^T rows (Ht[p][w]). SW=36 words = 9x16B row stride (odd) ->
//   uniform bank coverage for b128.
// Phase 2: lerp 12 nearest subnets + Gaussian PoU combine.

#define GK     5120
#define WIDTH  1024
#define HALFW  512
#define SW     36      // u32 words per LDS row: 32 data + 4 pad = 144 B

typedef _Float16 half8  __attribute__((ext_vector_type(8)));
typedef __fp16   fp16x2 __attribute__((ext_vector_type(2)));
typedef float    f32x4  __attribute__((ext_vector_type(4)));

__device__ __forceinline__ int glo_of(int s) {
    int g = (s * GK + 31) / 63 - HALFW;
    g = g < 0 ? 0 : g;
    const int hi = GK - (WIDTH - 1);
    g = g > hi ? hi : g;
    return g;
}

__device__ __forceinline__ float tanh_fast(float v) {
    // tanh(v) = 1 - 2/(exp(2v)+1); |v| <= ~7 here.
    float e = __expf(2.0f * v);
    return 1.0f - 2.0f * __builtin_amdgcn_rcpf(e + 1.0f);
}

__device__ __forceinline__ unsigned pkh(float a, float b) {
    fp16x2 h = __builtin_amdgcn_cvt_pkrtz(a, b);   // a->lo, b->hi
    return __builtin_bit_cast(unsigned, h);
}

// ---------------------------------------------------------------------------
// Phase 1. Grid: 64 subdomains x 16 chunks = 1024 blocks x 256 threads.
// ---------------------------------------------------------------------------
__global__ __launch_bounds__(256, 4) void eval_grid(
    const float* __restrict__ W0, const float* __restrict__ b0,
    const float* __restrict__ W1, const float* __restrict__ b1,
    const float* __restrict__ W2, const float* __restrict__ b2,
    const float* __restrict__ W3, const float* __restrict__ b3,
    float* __restrict__ U)
{
    const int tid  = (int)threadIdx.x;
    const int lane = tid & 63;
    const int wv   = __builtin_amdgcn_readfirstlane(tid >> 6);
    const int quad = lane >> 4;
    const int a16  = lane & 15;

    // XCD swizzle: subdomain = blockIdx mod 64 -> all 16 chunks of a
    // subdomain share one XCD's L2 under round-robin dispatch.
    const int s     = blockIdx.x & 63;
    const int chunk = blockIdx.x >> 6;
    const int glo   = glo_of(s);
    const float x   = (float)(glo + chunk * 64 + lane) * (1.0f / (float)GK);

    __shared__ unsigned HtA[64 * SW];   // h0, f16-pairs, rows = p
    __shared__ unsigned HtB[64 * SW];   // h1
    __shared__ unsigned Wa1[64 * SW];   // W1 f16, rows = v (A layout)
    __shared__ unsigned Wa2[64 * SW];
    __shared__ float    Pw[4][4][16];   // layer-3 partials [wv][ni][a16]

    // ---- stage W1, W2 as f16 rows (one-time; coalesced float4 loads)
    const float4* __restrict__ g1 = (const float4*)(W1 + s * 4096);
    const float4* __restrict__ g2 = (const float4*)(W2 + s * 4096);
#pragma unroll
    for (int q = 0; q < 4; ++q) {
        int li = q * 256 + tid;              // float4 index 0..1023
        int v  = li >> 4;                    // row
        int wd = 2 * (li & 15);              // word col (2 words per float4)
        float4 f1 = g1[li];
        float4 f2 = g2[li];
        Wa1[v * SW + wd]     = pkh(f1.x, f1.y);
        Wa1[v * SW + wd + 1] = pkh(f1.z, f1.w);
        Wa2[v * SW + wd]     = pkh(f2.x, f2.y);
        Wa2[v * SW + wd + 1] = pkh(f2.z, f2.w);
    }

    // ---- layer 0: wave wv computes v = 16wv..16wv+15 for its lane's point
    const float* __restrict__ w0  = W0 + s * 64;
    const float* __restrict__ bb0 = b0 + s * 64;
#pragma unroll
    for (int j = 0; j < 16; j += 2) {
        int v = 16 * wv + j;
        float h0 = tanh_fast(fmaf(w0[v],     x, bb0[v]));
        float h1 = tanh_fast(fmaf(w0[v + 1], x, bb0[v + 1]));
        HtA[lane * SW + (v >> 1)] = pkh(h0, h1);
    }
    __syncthreads();                         // h0 + Wa1 + Wa2 visible

    const int vbase = 16 * wv + 4 * quad;    // this lane's C rows (v)
    f32x4 acc[4];

    // ================= layer 1 (MFMA) =================
    {
        const float* __restrict__ b1g = b1 + s * 64;
        float bv[4];
#pragma unroll
        for (int r = 0; r < 4; ++r) bv[r] = b1g[vbase + r];
#pragma unroll
        for (int ni = 0; ni < 4; ++ni)
#pragma unroll
            for (int r = 0; r < 4; ++r) acc[ni][r] = bv[r];

        half8 afr[2];
#pragma unroll
        for (int ks = 0; ks < 2; ++ks)
            afr[ks] = *(const half8*)&Wa1[(16 * wv + a16) * SW + 16 * ks + 4 * quad];
#pragma unroll
        for (int ni = 0; ni < 4; ++ni) {
#pragma unroll
            for (int ks = 0; ks < 2; ++ks) {
                half8 bfr = *(const half8*)&HtA[(16 * ni + a16) * SW + 16 * ks + 4 * quad];
                acc[ni] = __builtin_amdgcn_mfma_f32_16x16x32_f16(afr[ks], bfr, acc[ni], 0, 0, 0);
            }
        }
        // tanh + pack h1 into HtB (rows = p, cols = v/2) — no WAR on HtA
#pragma unroll
        for (int ni = 0; ni < 4; ++ni) {
            int row  = (16 * ni + a16) * SW;
            int colb = 8 * wv + 2 * quad;
            HtB[row + colb]     = pkh(tanh_fast(acc[ni][0]), tanh_fast(acc[ni][1]));
            HtB[row + colb + 1] = pkh(tanh_fast(acc[ni][2]), tanh_fast(acc[ni][3]));
        }
    }
    __syncthreads();                         // h1 visible

    // ================= layer 2 (MFMA) =================
    {
        const float* __restrict__ b2g = b2 + s * 64;
        float bv[4];
#pragma unroll
        for (int r = 0; r < 4; ++r) bv[r] = b2g[vbase + r];
#pragma unroll
        for (int ni = 0; ni < 4; ++ni)
#pragma unroll
            for (int r = 0; r < 4; ++r) acc[ni][r] = bv[r];

        half8 afr[2];
#pragma unroll
        for (int ks = 0; ks < 2; ++ks)
            afr[ks] = *(const half8*)&Wa2[(16 * wv + a16) * SW + 16 * ks + 4 * quad];
#pragma unroll
        for (int ni = 0; ni < 4; ++ni) {
#pragma unroll
            for (int ks = 0; ks < 2; ++ks) {
                half8 bfr = *(const half8*)&HtB[(16 * ni + a16) * SW + 16 * ks + 4 * quad];
                acc[ni] = __builtin_amdgcn_mfma_f32_16x16x32_f16(afr[ks], bfr, acc[ni], 0, 0, 0);
            }
        }
    }

    // ================= layer 3: u[p] = b3 + sum_v w3[v]*tanh(h2[v][p]) ====
    {
        const float* __restrict__ w3g = W3 + s * 64;
        float w3r[4];
#pragma unroll
        for (int r = 0; r < 4; ++r) w3r[r] = w3g[vbase + r];
#pragma unroll
        for (int ni = 0; ni < 4; ++ni) {
            float pu = 0.0f;
#pragma unroll
            for (int r = 0; r < 4; ++r)
                pu = fmaf(w3r[r], tanh_fast(acc[ni][r]), pu);
            // sum over the 4 quads (v-subsets) for fixed p = 16ni + a16
            pu += __shfl_xor(pu, 16);
            pu += __shfl_xor(pu, 32);
            if (quad == 0) Pw[wv][ni][a16] = pu;
        }
    }
    __syncthreads();

    if (tid < 64) {
        float u = b3[s];
#pragma unroll
        for (int w = 0; w < 4; ++w) u += Pw[w][tid >> 4][tid & 15];
        U[s * WIDTH + chunk * 64 + tid] = u;
    }
}

// ---------------------------------------------------------------------------
// Phase 2: PoU combine over the 12 nearest subdomains via table lerp.
// 512 x 128 for gather-latency TLP.
// ---------------------------------------------------------------------------
__global__ __launch_bounds__(128) void combine(
    const float* __restrict__ x_in, const float* __restrict__ U,
    float* __restrict__ out, int N)
{
    int n = blockIdx.x * 128 + (int)threadIdx.x;
    if (n >= N) return;
    float x = x_in[n];

    int jf = (int)floorf(x * 63.0f);    // floor center index
    int lo = jf - 5;                    // window jf-5 .. jf+6 (12 subnets)
    lo = lo < 0 ? 0 : (lo > 52 ? 52 : lo);

    const float inv_sigma = 64.0f / 1.5f;
    const float t_all = x * (float)GK;

    float u0v[12], u1v[12], fracv[12], wvv[12];
#pragma unroll
    for (int k = 0; k < 12; ++k) {
        int s = lo + k;
        int glo = glo_of(s);
        float t = t_all - (float)glo;
        int it = (int)floorf(t);
        it = it < 0 ? 0 : (it > WIDTH - 2 ? WIDTH - 2 : it);
        fracv[k] = t - (float)it;
        const float* __restrict__ row = U + s * WIDTH + it;
        u0v[k] = row[0];
        u1v[k] = row[1];
        float d = (x - (float)s * (1.0f / 63.0f)) * inv_sigma;
        wvv[k] = __expf(-0.5f * d * d);
    }

    float num = 0.0f, den = 0.0f;
#pragma unroll
    for (int k = 0; k < 12; ++k) {
        float u = fmaf(fracv[k], u1v[k] - u0v[k], u0v[k]);
        num = fmaf(wvv[k], u, num);
        den += wvv[k];
    }

    out[n] = tanh_fast(5.0f * x) * num * __builtin_amdgcn_rcpf(den);
}

// ---------------------------------------------------------------------------
extern "C" void kernel_launch(void* const* d_in, const int* in_sizes, int n_in,
                              void* d_out, int out_size, void* d_ws, size_t ws_size,
                              hipStream_t stream) {
    const float* x  = (const float*)d_in[0];
    const float* W0 = (const float*)d_in[1];
    const float* b0 = (const float*)d_in[2];
    const float* W1 = (const float*)d_in[3];
    const float* b1 = (const float*)d_in[4];
    const float* W2 = (const float*)d_in[5];
    const float* b2 = (const float*)d_in[6];
    const float* W3 = (const float*)d_in[7];
    const float* b3 = (const float*)d_in[8];

    float* U   = (float*)d_ws;     // 64 * 1024 * 4 B = 256 KiB scratch
    float* out = (float*)d_out;

    eval_grid<<<dim3(1024), dim3(256), 0, stream>>>(
        W0, b0, W1, b1, W2, b2, W3, b3, U);
    combine<<<dim3(512), dim3(128), 0, stream>>>(x, U, out, 65536);
}